// Round 1
// baseline (439.287 us; speedup 1.0000x reference)
//
#include <hip/hip_runtime.h>
#include <math.h>

#define Bz 32
#define Lz 2048
#define Hz 768
#define Tz 12
#define Ez 7
#define EMPTYIDX 6
#define NCOL 24              // T*2 logit columns per batch
#define NITEM (Bz * Tz)      // 384 (b,t) pairs
#define LCHUNK 128
#define NCHUNK 16            // Lz / LCHUNK

// ---------------- kernel 0: bin (b,t) pairs by module index e ----------------
__global__ void k0_compact(const int* __restrict__ midx,
                           int* __restrict__ off, int* __restrict__ items) {
    __shared__ int cnt[Ez];
    __shared__ int offs[Ez + 1];
    int tid = threadIdx.x;                 // 384 threads, one per (b,t)
    if (tid < Ez) cnt[tid] = 0;
    __syncthreads();
    int e = midx[tid];
    e = min(max(e, 0), Ez - 1);
    int r = atomicAdd(&cnt[e], 1);
    __syncthreads();
    if (tid == 0) {
        int acc = 0;
        for (int j = 0; j < Ez; ++j) { offs[j] = acc; acc += cnt[j]; }
        offs[Ez] = acc;
    }
    __syncthreads();
    items[offs[e] + r] = tid;
    if (tid <= Ez) off[tid] = offs[tid];
}

// ---------------- kernel 1a: cW partial dots, H split across blocks ----------
// grid = Ez(7) * ZC(3) * HC(16) = 336 blocks, 256 threads.
// W[e] 48h x 256z slab in registers (read from HBM exactly once). Partial for
// h-chunk hc stored to a DISJOINT buffer pc[hc][i][z] (plain coalesced store)
// -- no atomics, no memset dependency. Reduced over hc in k1b.
#define K1A_ZC 3
#define K1A_HB 48
#define K1A_HC 16
__global__ void k1a_cw(const float* __restrict__ seq, const float* __restrict__ W,
                       const int* __restrict__ turns,
                       const int* __restrict__ off, const int* __restrict__ items,
                       float* __restrict__ pc) {
    int bx = blockIdx.x;
    int e  = bx % Ez;
    int zc = (bx / Ez) % K1A_ZC;
    int hc = bx / (Ez * K1A_ZC);           // 0..15
    int z  = zc * 256 + threadIdx.x;       // 0..767
    int h0 = hc * K1A_HB;
    int off0 = off[e];
    int cnt  = off[e + 1] - off0;
    const float* Wb = W + ((size_t)e * Hz + h0) * Hz + z;
    float w[K1A_HB];
#pragma unroll
    for (int j = 0; j < K1A_HB; ++j) w[j] = Wb[(size_t)j * Hz];

    for (int n = 0; n < cnt; ++n) {
        int i  = items[off0 + n];          // wave-uniform in practice
        int b  = i / Tz;
        int st = turns[2 * i];
        st = min(max(st, 0), Lz - 1);
        const float* c = seq + ((size_t)(b * Lz + st)) * Hz + h0;
        float acc = 0.f;
#pragma unroll
        for (int j = 0; j < K1A_HB; ++j) acc = fmaf(c[j], w[j], acc);
        pc[((size_t)hc * NITEM + i) * Hz + z] = acc;   // disjoint -> plain store
    }
}

// ---------------- kernel 1b: reduce hc partials, v = cW * spanw --------------
__global__ void k1b_v(const float* __restrict__ pc, const float* __restrict__ spanw,
                      const int* __restrict__ midx, float* __restrict__ v) {
    int idx = blockIdx.x * 256 + threadIdx.x;   // 384*768 = 294912
    int i = idx / Hz;
    int z = idx - i * Hz;
    float cw = 0.f;
#pragma unroll
    for (int hc = 0; hc < K1A_HC; ++hc)
        cw += pc[((size_t)hc * NITEM + i) * Hz + z];
    int e = midx[i];
    e = min(max(e, 0), Ez - 1);
    int b = i / Tz, t = i - b * Tz;
    size_t vb = ((size_t)(b * NCOL + t * 2)) * Hz + z;
    v[vb]      = cw * spanw[(e * Hz + z) * 2 + 0];
    v[vb + Hz] = cw * spanw[(e * Hz + z) * 2 + 1];
}

// ---------------- kernel 2: logits GEMM + chunk logsumexp + picked -----------
// grid = Bz*NCHUNK = 512 blocks (2/CU), 256 threads.
// Row-per-thread formulation: thread owns one seq row (r = tid&127) and ALL 24
// output columns in registers; tid>>7 selects which 32-wide k-half the thread
// accumulates (wave-uniform -> readfirstlane). Per 64-k phase each thread does
// 8 ds_read_b128 (its own row, XOR-swizzled staging keeps b128 at the
// conflict-free 8-dword/bank floor) feeding 768 FMAs -- a ~12x cut in LDS
// instructions vs the old 4x3-tile version. The V operand address depends only
// on blockIdx + loop constants + a readfirstlane'd k-half, i.e. provably
// uniform + no-clobber (__restrict__) -> compiler promotes to s_load on the
// SMEM pipe (SGPR operand of v_fmac); worst case it's an L1-resident broadcast
// VMEM load (the 3 KB phase slice of v stays in L1). k3 (picked) is fused into
// the epilogue: the thread owning the target row already has the logit.
#define BKP 64               // k floats staged per phase (both halves)
#define NPH (Hz / BKP)       // 12
__global__ __launch_bounds__(256, 2)
void k2_logits(const float* __restrict__ seq, const float* __restrict__ v,
               const int* __restrict__ kps,
               float* __restrict__ pm, float* __restrict__ ps,
               float* __restrict__ picked) {
    int bx  = blockIdx.x;
    int b   = bx / NCHUNK;
    int ch  = bx % NCHUNK;
    int l0  = ch * LCHUNK;
    int tid = threadIdx.x;
    int r   = tid & (LCHUNK - 1);                       // row within chunk
    int kh  = __builtin_amdgcn_readfirstlane(tid >> 7); // k-half, wave-uniform

    __shared__ float at[LCHUNK][BKP];        // 32 KB, XOR-swizzled 16B groups
    __shared__ float lg[LCHUNK][NCOL + 1];   // merged logits, 12.8 KB
    __shared__ float redm[NCOL][4], reds[NCOL][4];
    __shared__ int   ksafe[NCOL];

    if (tid < NCOL) {                        // kps (B,T,2) -> b*24 + col
        int t0 = kps[b * NCOL + tid];
        ksafe[tid] = min(max(t0, 0), Lz - 1);
    }

    float acc[NCOL];
#pragma unroll
    for (int c = 0; c < NCOL; ++c) acc[c] = 0.f;

    const float* A = seq + ((size_t)b * Lz + l0) * Hz;
    const float* V = v + (size_t)b * NCOL * Hz;

    // prologue: phase-0 global loads into registers
    float4 g[8];
#pragma unroll
    for (int p = 0; p < 8; ++p) {
        int j = tid + p * 256, rr = j >> 4, c4 = j & 15;
        g[p] = *(const float4*)&A[(size_t)rr * Hz + c4 * 4];
    }

    for (int ph = 0; ph < NPH; ++ph) {
        __syncthreads();                      // prev compute done reading at
#pragma unroll
        for (int p = 0; p < 8; ++p) {         // swizzled stage: slot = c4 ^ (row&15)
            int j = tid + p * 256, rr = j >> 4, c4 = j & 15;
            *(float4*)&at[rr][((c4 ^ (rr & 15)) << 2)] = g[p];
        }
        __syncthreads();
        if (ph + 1 < NPH) {                   // issue next-phase loads early;
#pragma unroll                                 // HBM latency hides under compute
            for (int p = 0; p < 8; ++p) {
                int j = tid + p * 256, rr = j >> 4, c4 = j & 15;
                g[p] = *(const float4*)&A[(size_t)rr * Hz + (ph + 1) * BKP + c4 * 4];
            }
        }
        // this thread's 32 A-floats for its k-half, read once, reused x24 cols
        float a[32];
#pragma unroll
        for (int q4 = 0; q4 < 8; ++q4) {
            int c4 = kh * 8 + q4;
            float4 x = *(const float4*)&at[r][((c4 ^ (r & 15)) << 2)];
            a[q4 * 4 + 0] = x.x; a[q4 * 4 + 1] = x.y;
            a[q4 * 4 + 2] = x.z; a[q4 * 4 + 3] = x.w;
        }
        const float* Vp = V + ph * BKP + kh * 32;   // uniform per wave
#pragma unroll 2
        for (int c = 0; c < NCOL; ++c) {
            const float* vp = Vp + (size_t)c * Hz;
            float s0 = 0.f, s1 = 0.f;
#pragma unroll
            for (int q = 0; q < 32; q += 2) {
                s0 = fmaf(a[q],     vp[q],     s0);
                s1 = fmaf(a[q + 1], vp[q + 1], s1);
            }
            acc[c] += s0 + s1;
        }
    }

    // merge the two k-halves: rows r held by tid and tid+128
    if (kh == 1) {
#pragma unroll
        for (int c = 0; c < NCOL; ++c) lg[r][c] = acc[c];
    }
    __syncthreads();
    if (kh == 0) {
#pragma unroll
        for (int c = 0; c < NCOL; ++c) { acc[c] += lg[r][c]; lg[r][c] = acc[c]; }
        // fused k3: the thread owning the target row emits the picked logit
        int grow = l0 + r;
#pragma unroll
        for (int c = 0; c < NCOL; ++c)
            if (ksafe[c] == grow) picked[b * NCOL + c] = acc[c];
    }
    __syncthreads();

    // chunk logsumexp partials: 96 threads = 24 cols x 4 row-quarters
    if (tid < 96) {
        int c = tid >> 2, rg = tid & 3;
        float m = lg[rg * 32][c];
        for (int rr = rg * 32 + 1; rr < rg * 32 + 32; ++rr)
            m = fmaxf(m, lg[rr][c]);
        float s = 0.f;
        for (int rr = rg * 32; rr < rg * 32 + 32; ++rr)
            s += expf(lg[rr][c] - m);
        redm[c][rg] = m; reds[c][rg] = s;
    }
    __syncthreads();
    if (tid < NCOL) {
        float m = redm[tid][0];
        for (int j = 1; j < 4; ++j) m = fmaxf(m, redm[tid][j]);
        float s = 0.f;
        for (int j = 0; j < 4; ++j) s += reds[tid][j] * expf(redm[tid][j] - m);
        pm[((size_t)b * NCOL + tid) * NCHUNK + ch] = m;
        ps[((size_t)b * NCOL + tid) * NCHUNK + ch] = s;
    }
}

// ---------------- kernel 4: combine partials -> ce -> masked-mean loss -------
__global__ void k4_final(const int* __restrict__ midx, const int* __restrict__ turns,
                         const int* __restrict__ kps,
                         const float* __restrict__ pm, const float* __restrict__ ps,
                         const float* __restrict__ picked, float* __restrict__ out) {
    int tid = threadIdx.x;                 // 384 threads, one per (b,t)
    int i = tid;
    int b = i / Tz, t = i % Tz;
    int e = midx[i];
    float modm  = (e != EMPTYIDX) ? 1.f : 0.f;
    float tmask = (turns[2 * i] >= 0) ? 1.f : 0.f;
    float ce[2];
#pragma unroll
    for (int k = 0; k < 2; ++k) {
        int c = t * 2 + k;
        const float* pmr = pm + ((size_t)b * NCOL + c) * NCHUNK;
        const float* psr = ps + ((size_t)b * NCOL + c) * NCHUNK;
        float m = pmr[0];
        for (int chn = 1; chn < NCHUNK; ++chn) m = fmaxf(m, pmr[chn]);
        float s = 0.f;
        for (int chn = 0; chn < NCHUNK; ++chn) s += psr[chn] * expf(pmr[chn] - m);
        float lse = m + logf(s);
        int tgt = kps[2 * i + k];
        ce[k] = (tgt >= 0) ? (lse - picked[b * NCOL + c]) : 0.f;
    }
    float contrib = 0.5f * (ce[0] + ce[1]) * modm * tmask;

    __shared__ float wsum[6], wmask[6];
    float sl = contrib, sm = tmask;
    for (int o = 32; o > 0; o >>= 1) {
        sl += __shfl_down(sl, o, 64);
        sm += __shfl_down(sm, o, 64);
    }
    int w = tid >> 6, lane = tid & 63;
    if (lane == 0) { wsum[w] = sl; wmask[w] = sm; }
    __syncthreads();
    if (tid == 0) {
        float a = 0.f, mk = 0.f;
        for (int ww = 0; ww < 6; ++ww) { a += wsum[ww]; mk += wmask[ww]; }
        out[0] = a / mk;
    }
}

extern "C" void kernel_launch(void* const* d_in, const int* in_sizes, int n_in,
                              void* d_out, int out_size, void* d_ws, size_t ws_size,
                              hipStream_t stream) {
    const float* seq   = (const float*)d_in[0];  // (32,2048,768)
    const float* W     = (const float*)d_in[1];  // (7,768,768)
    const float* spanw = (const float*)d_in[2];  // (7,768,2)
    const int*   turns = (const int*)d_in[3];    // (32,12,2)
    const int*   kps   = (const int*)d_in[4];    // (32,12,2)
    const int*   midx  = (const int*)d_in[5];    // (32,12)
    float* out = (float*)d_out;

    // workspace layout (needs ~21.4 MB; the 768 MB poison fills in the profile
    // indicate the allocation is far larger)
    char* ws = (char*)d_ws;
    int*   off    = (int*)(ws + 0);                              // 8 ints
    int*   items  = (int*)(ws + 256);                            // 384 ints
    float* pc     = (float*)(ws + 2048);                         // 16*384*768 f32 = 18,874,368 B
    float* v      = (float*)(ws + 2048 + 18874368);              // 32*24*768 f32 =  2,359,296 B
    float* pm     = (float*)(ws + 2048 + 18874368 + 2359296);            // 49,152 B
    float* ps     = (float*)(ws + 2048 + 18874368 + 2359296 + 49152);    // 49,152 B
    float* picked = (float*)(ws + 2048 + 18874368 + 2359296 + 98304);    //  1,536 B

    hipLaunchKernelGGL(k0_compact, dim3(1), dim3(NITEM), 0, stream, midx, off, items);
    hipLaunchKernelGGL(k1a_cw, dim3(Ez * K1A_ZC * K1A_HC), dim3(256), 0, stream,
                       seq, W, turns, off, items, pc);
    hipLaunchKernelGGL(k1b_v, dim3((NITEM * Hz) / 256), dim3(256), 0, stream,
                       pc, spanw, midx, v);
    hipLaunchKernelGGL(k2_logits, dim3(Bz * NCHUNK), dim3(256), 0, stream,
                       seq, v, kps, pm, ps, picked);
    hipLaunchKernelGGL(k4_final, dim3(1), dim3(NITEM), 0, stream,
                       midx, turns, kps, pm, ps, picked, out);
}